// Round 1
// baseline (19564.815 us; speedup 1.0000x reference)
//
#include <hip/hip_runtime.h>
#include <hip/hip_bf16.h>
#include <math.h>

// Problem constants (from reference)
//  Tx=48 Ty=48 Bn=64 DW=512 E=512 D=1024 A=512 VS=VT=32000
// All fp32. Output: single scalar (sum of per-step losses).

typedef float f4 __attribute__((ext_vector_type(4)));

__device__ __forceinline__ f4 ld4(const float* p) { return *reinterpret_cast<const f4*>(p); }
__device__ __forceinline__ float sigf(float x) { return 1.0f / (1.0f + expf(-x)); }

// ---------------------------------------------------------------------------
// Generic tiled GEMM:  C[M,N] = act( A(M,K,lda) @ B(N,K,ldb)^T + bias + Cin )
// BM=BN=64, BK=32, 256 threads, 4x4 micro-tile per thread.
// MAXP: A is r_pre (64, 2K) and logical A[m][k] = max(r_pre[m][2k], r_pre[m][2k+1]).
// blockIdx.z==1 selects the second (dual) problem (same M,N,K).
// ---------------------------------------------------------------------------
template<int ACT, int MAXP>
__global__ __launch_bounds__(256) void gemm_nt(
    const float* __restrict__ A, int lda,
    const float* __restrict__ B, int ldb,
    const float* __restrict__ bias,
    const float* __restrict__ Cin,
    float* __restrict__ C,
    int N, int K,
    const float* A2, const float* B2, const float* bias2,
    const float* Cin2, float* C2)
{
    if (blockIdx.z == 1) { A = A2; B = B2; bias = bias2; Cin = Cin2; C = C2; }
    __shared__ float As[32][68];
    __shared__ float Bs[32][68];
    const int tid = threadIdx.x;
    const int bn = blockIdx.x * 64;
    const int bm = blockIdx.y * 64;
    const int row = tid >> 2;          // 0..63
    const int kq  = (tid & 3) << 2;    // 0,4,8,12
    const int tx = tid & 15, ty = tid >> 4;
    float acc[4][4] = {};

    const float* Arow = A + (size_t)(bm + row) * lda;
    const float* Brow = B + (size_t)(bn + row) * ldb;

    for (int k0 = 0; k0 < K; k0 += 32) {
        f4 a0, a1;
        if constexpr (MAXP) {
            f4 p0 = ld4(Arow + 2 * (k0 + kq));
            f4 p1 = ld4(Arow + 2 * (k0 + kq) + 4);
            f4 q0 = ld4(Arow + 2 * (k0 + 16 + kq));
            f4 q1 = ld4(Arow + 2 * (k0 + 16 + kq) + 4);
            a0.x = fmaxf(p0.x, p0.y); a0.y = fmaxf(p0.z, p0.w);
            a0.z = fmaxf(p1.x, p1.y); a0.w = fmaxf(p1.z, p1.w);
            a1.x = fmaxf(q0.x, q0.y); a1.y = fmaxf(q0.z, q0.w);
            a1.z = fmaxf(q1.x, q1.y); a1.w = fmaxf(q1.z, q1.w);
        } else {
            a0 = ld4(Arow + k0 + kq);
            a1 = ld4(Arow + k0 + 16 + kq);
        }
        f4 b0 = ld4(Brow + k0 + kq);
        f4 b1 = ld4(Brow + k0 + 16 + kq);
        __syncthreads();   // protect previous iteration's reads
        As[kq + 0][row] = a0.x; As[kq + 1][row] = a0.y;
        As[kq + 2][row] = a0.z; As[kq + 3][row] = a0.w;
        As[kq + 16][row] = a1.x; As[kq + 17][row] = a1.y;
        As[kq + 18][row] = a1.z; As[kq + 19][row] = a1.w;
        Bs[kq + 0][row] = b0.x; Bs[kq + 1][row] = b0.y;
        Bs[kq + 2][row] = b0.z; Bs[kq + 3][row] = b0.w;
        Bs[kq + 16][row] = b1.x; Bs[kq + 17][row] = b1.y;
        Bs[kq + 18][row] = b1.z; Bs[kq + 19][row] = b1.w;
        __syncthreads();
        #pragma unroll
        for (int k = 0; k < 32; ++k) {
            f4 av = *(const f4*)&As[k][ty * 4];
            f4 bv = *(const f4*)&Bs[k][tx * 4];
            #pragma unroll
            for (int i = 0; i < 4; ++i)
                #pragma unroll
                for (int j = 0; j < 4; ++j)
                    acc[i][j] += av[i] * bv[j];
        }
    }

    #pragma unroll
    for (int i = 0; i < 4; ++i) {
        int m = bm + ty * 4 + i;
        int n0 = bn + tx * 4;
        f4 v; v.x = acc[i][0]; v.y = acc[i][1]; v.z = acc[i][2]; v.w = acc[i][3];
        if (bias) {
            v.x += bias[n0 + 0]; v.y += bias[n0 + 1];
            v.z += bias[n0 + 2]; v.w += bias[n0 + 3];
        }
        if (Cin) {
            f4 ci = ld4(Cin + (size_t)m * N + n0);
            v.x += ci.x; v.y += ci.y; v.z += ci.z; v.w += ci.w;
        }
        if constexpr (ACT == 1) {
            v.x = tanhf(v.x); v.y = tanhf(v.y); v.z = tanhf(v.z); v.w = tanhf(v.w);
        }
        *reinterpret_cast<f4*>(C + (size_t)m * N + n0) = v;
    }
}

// ---------------------------------------------------------------------------
// Embeddings: blockIdx.y==0 -> x_emb = src_emb[x]*mask ; ==1 -> y_emb (y_prev)
// ---------------------------------------------------------------------------
__global__ void embed_kernel(const int* __restrict__ xd, const float* __restrict__ xm,
                             const int* __restrict__ yd,
                             const float* __restrict__ src_emb, const float* __restrict__ dec_emb,
                             float* __restrict__ x_emb, float* __restrict__ y_emb)
{
    int idx = blockIdx.x * 256 + threadIdx.x;   // 48*64*512
    int d = idx & 511;
    int tb = idx >> 9;
    if (blockIdx.y == 0) {
        int v = xd[tb];
        x_emb[idx] = src_emb[(size_t)v * 512 + d] * xm[tb];
    } else {
        int t = tb >> 6, b = tb & 63;
        int v = (t == 0) ? 0 : yd[(t - 1) * 64 + b];
        y_emb[idx] = dec_emb[(size_t)v * 512 + d];
    }
}

// Build concatenated cell weight Wz (4096, 2560): [ctx part | Whh | y part]
__global__ void build_wz(const float* __restrict__ Wih, const float* __restrict__ Whh,
                         float* __restrict__ Wz)
{
    int idx = blockIdx.x * 256 + threadIdx.x;  // 4096*2560
    int j = idx % 2560; int n = idx / 2560;
    float v;
    if (j < 1024)      v = Wih[(size_t)n * 1536 + 512 + j];
    else if (j < 2048) v = Whh[(size_t)n * 1024 + (j - 1024)];
    else               v = Wih[(size_t)n * 1536 + (j - 2048)];
    Wz[idx] = v;
}

__global__ void zero_kernel(float* __restrict__ p) {
    p[blockIdx.x * 256 + threadIdx.x] = 0.0f;
}

// Encoder LSTM gates, both directions (blockIdx.y = dir)
__global__ void enc_gates(const float* __restrict__ z_f, const float* __restrict__ z_r,
                          float* __restrict__ h_f, float* __restrict__ c_f,
                          float* __restrict__ h_r, float* __restrict__ c_r,
                          float* __restrict__ out_f, float* __restrict__ out_r,
                          int t_f, int t_r)
{
    int dir = blockIdx.y;
    int idx = blockIdx.x * 256 + threadIdx.x;  // 64*512
    int b = idx >> 9, d = idx & 511;
    const float* z = dir ? z_r : z_f;
    float* h = dir ? h_r : h_f;
    float* c = dir ? c_r : c_f;
    float* op = dir ? (out_r + (size_t)t_r * 64 * 512) : (out_f + (size_t)t_f * 64 * 512);
    float iv = z[b * 2048 + d];
    float fv = z[b * 2048 + 512 + d];
    float gv = z[b * 2048 + 1024 + d];
    float ov = z[b * 2048 + 1536 + d];
    float cn = sigf(fv) * c[idx] + sigf(iv) * tanhf(gv);
    float hn = sigf(ov) * tanhf(cn);
    c[idx] = cn; h[idx] = hn; op[idx] = hn;
}

// ctx = concat(out_f, out_r) * mask
__global__ void build_ctx(const float* __restrict__ out_f, const float* __restrict__ out_r,
                          const float* __restrict__ xm, float* __restrict__ ctx)
{
    int idx = blockIdx.x * 256 + threadIdx.x;  // 48*64*1024
    int e = idx & 1023; int tb = idx >> 10;
    float v = (e < 512) ? out_f[(size_t)tb * 512 + e] : out_r[(size_t)tb * 512 + e - 512];
    ctx[idx] = v * xm[tb];
}

__global__ __launch_bounds__(256) void ctx_mean_k(const float* __restrict__ ctx,
                                                  const float* __restrict__ xm,
                                                  float* __restrict__ cm)
{
    int b = blockIdx.x; int tid = threadIdx.x;
    float msum = 0.0f;
    for (int t = 0; t < 48; ++t) msum += xm[t * 64 + b];
    float inv = 1.0f / msum;
    for (int e = tid; e < 1024; e += 256) {
        float s = 0.0f;
        for (int t = 0; t < 48; ++t) s += ctx[(size_t)(t * 64 + b) * 1024 + e] * xm[t * 64 + b];
        cm[b * 1024 + e] = s * inv;
    }
}

__global__ void ht_to_cat3(const float* __restrict__ ht, float* __restrict__ cat3)
{
    int idx = blockIdx.x * 256 + threadIdx.x;  // 64*1024
    int b = idx >> 10, d = idx & 1023;
    cat3[b * 2560 + 1024 + d] = ht[idx];
}

// ---------------------------------------------------------------------------
// Fused attention step, one block per batch row b (512 threads):
//   a2[t'] = att2_W . tanh(att_ctx[t',b,:] + preY[t,b,:] + hW1h[b,:]) + att2_b
//   alpha = softmax_t'(a2) * mask (per-b max; eps 1e-15 negligible)
//   cat3[b, 0:1024]   = sum_t' alpha[t'] * ctx[t',b,:]
//   cat3[b, 2048:2560]= y_emb[t,b,:]
// ---------------------------------------------------------------------------
__global__ __launch_bounds__(512) void att_step(
    const float* __restrict__ att_ctx, const float* __restrict__ preY_t,
    const float* __restrict__ hW1h, const float* __restrict__ att2W,
    const float* __restrict__ att2b, const float* __restrict__ xmask,
    const float* __restrict__ ctx, const float* __restrict__ yemb_t,
    float* __restrict__ cat3)
{
    int b = blockIdx.x;
    int tid = threadIdx.x;
    __shared__ float sv[512];
    __shared__ float a2s[64];
    sv[tid] = preY_t[b * 512 + tid] + hW1h[b * 512 + tid];
    __syncthreads();
    int wave = tid >> 6, lane = tid & 63;
    for (int tp = wave; tp < 48; tp += 8) {
        const float* ac = att_ctx + (size_t)(tp * 64 + b) * 512;
        float s = 0.0f;
        #pragma unroll
        for (int a0 = 0; a0 < 512; a0 += 64) {
            int a = a0 + lane;
            s += att2W[a] * tanhf(ac[a] + sv[a]);
        }
        for (int m = 32; m; m >>= 1) s += __shfl_xor(s, m);
        if (lane == 0) a2s[tp] = s + att2b[0];
    }
    __syncthreads();
    if (tid < 64) {
        float v = (tid < 48) ? a2s[tid] : -1e30f;
        float m = v;
        for (int sh = 32; sh; sh >>= 1) m = fmaxf(m, __shfl_xor(m, sh));
        float e = (tid < 48) ? expf(v - m) * xmask[tid * 64 + b] : 0.0f;
        float s = e;
        for (int sh = 32; sh; sh >>= 1) s += __shfl_xor(s, sh);
        if (tid < 48) a2s[tid] = e / (s + 1e-15f);
    }
    __syncthreads();
    for (int e0 = tid; e0 < 1024; e0 += 512) {
        float acc = 0.0f;
        for (int tp = 0; tp < 48; ++tp)
            acc += a2s[tp] * ctx[(size_t)(tp * 64 + b) * 1024 + e0];
        cat3[b * 2560 + e0] = acc;
    }
    cat3[b * 2560 + 2048 + tid] = yemb_t[b * 512 + tid];
}

// Decoder LSTM gates; writes new ht into cat3's ht slot for the read GEMM.
__global__ void dec_gates(const float* __restrict__ z, float* __restrict__ ht,
                          float* __restrict__ ct, float* __restrict__ cat3)
{
    int idx = blockIdx.x * 256 + threadIdx.x;  // 64*1024
    int b = idx >> 10, d = idx & 1023;
    float iv = z[b * 4096 + d];
    float fv = z[b * 4096 + 1024 + d];
    float gv = z[b * 4096 + 2048 + d];
    float ov = z[b * 4096 + 3072 + d];
    float cn = sigf(fv) * ct[idx] + sigf(iv) * tanhf(gv);
    float hn = sigf(ov) * tanhf(cn);
    ct[idx] = cn; ht[idx] = hn; cat3[b * 2560 + 1024 + d] = hn;
}

// log-softmax + NLL over 32000 classes; one block per batch row.
__global__ __launch_bounds__(256) void lsm_nll(const float* __restrict__ logits,
                                               const int* __restrict__ yd_t,
                                               const float* __restrict__ ym_t,
                                               float* __restrict__ lossb_t)
{
    __shared__ float red[4];
    int b = blockIdx.x, tid = threadIdx.x;
    const float* row = logits + (size_t)b * 32000;
    float m = -1e30f;
    for (int i = tid; i < 32000; i += 256) m = fmaxf(m, row[i]);
    for (int sh = 32; sh; sh >>= 1) m = fmaxf(m, __shfl_xor(m, sh));
    if ((tid & 63) == 0) red[tid >> 6] = m;
    __syncthreads();
    m = fmaxf(fmaxf(red[0], red[1]), fmaxf(red[2], red[3]));
    __syncthreads();
    float s = 0.0f;
    for (int i = tid; i < 32000; i += 256) s += expf(row[i] - m);
    for (int sh = 32; sh; sh >>= 1) s += __shfl_xor(s, sh);
    if ((tid & 63) == 0) red[tid >> 6] = s;
    __syncthreads();
    if (tid == 0) {
        s = red[0] + red[1] + red[2] + red[3];
        int y = yd_t[b];
        float lp = row[y] - m - logf(s);
        lossb_t[b] = -lp * ym_t[b] * (1.0f / 64.0f);
    }
}

__global__ __launch_bounds__(256) void final_sum(const float* __restrict__ lossb,
                                                 float* __restrict__ out)
{
    __shared__ float red[4];
    int tid = threadIdx.x;
    float s = 0.0f;
    for (int i = tid; i < 3072; i += 256) s += lossb[i];
    for (int sh = 32; sh; sh >>= 1) s += __shfl_xor(s, sh);
    if ((tid & 63) == 0) red[tid >> 6] = s;
    __syncthreads();
    if (tid == 0) out[0] = red[0] + red[1] + red[2] + red[3];
}

// ---------------------------------------------------------------------------
// Host side
// ---------------------------------------------------------------------------
static void gemm(hipStream_t st, int act, int maxp,
                 const float* A, int lda, const float* B, int ldb,
                 const float* bias, const float* Cin, float* C,
                 int M, int N, int K,
                 const float* A2 = nullptr, const float* B2 = nullptr,
                 const float* bias2 = nullptr, const float* Cin2 = nullptr,
                 float* C2 = nullptr)
{
    dim3 grid(N / 64, M / 64, A2 ? 2 : 1);
    dim3 blk(256);
    if (maxp)
        hipLaunchKernelGGL((gemm_nt<0,1>), grid, blk, 0, st, A, lda, B, ldb, bias, Cin, C, N, K, A2, B2, bias2, Cin2, C2);
    else if (act == 1)
        hipLaunchKernelGGL((gemm_nt<1,0>), grid, blk, 0, st, A, lda, B, ldb, bias, Cin, C, N, K, A2, B2, bias2, Cin2, C2);
    else
        hipLaunchKernelGGL((gemm_nt<0,0>), grid, blk, 0, st, A, lda, B, ldb, bias, Cin, C, N, K, A2, B2, bias2, Cin2, C2);
}

extern "C" void kernel_launch(void* const* d_in, const int* in_sizes, int n_in,
                              void* d_out, int out_size, void* d_ws, size_t ws_size,
                              hipStream_t stream)
{
    const int*   x_data    = (const int*)d_in[0];
    const float* x_mask    = (const float*)d_in[1];
    const int*   y_data    = (const int*)d_in[2];
    const float* y_mask    = (const float*)d_in[3];
    const float* src_emb   = (const float*)d_in[4];
    const float* dec_emb   = (const float*)d_in[5];
    const float* enc_Wih_f = (const float*)d_in[6];
    const float* enc_Whh_f = (const float*)d_in[7];
    const float* enc_b_f   = (const float*)d_in[8];
    const float* enc_Wih_r = (const float*)d_in[9];
    const float* enc_Whh_r = (const float*)d_in[10];
    const float* enc_b_r   = (const float*)d_in[11];
    const float* h0_W      = (const float*)d_in[12];
    const float* h0_b      = (const float*)d_in[13];
    const float* c0_W      = (const float*)d_in[14];
    const float* c0_b      = (const float*)d_in[15];
    const float* att1_W    = (const float*)d_in[16];
    const float* att1_b    = (const float*)d_in[17];
    const float* att2_W    = (const float*)d_in[18];
    const float* att2_b    = (const float*)d_in[19];
    const float* cell_Wih  = (const float*)d_in[20];
    const float* cell_Whh  = (const float*)d_in[21];
    const float* cell_b    = (const float*)d_in[22];
    const float* read_W    = (const float*)d_in[23];
    const float* read_b    = (const float*)d_in[24];
    const float* out_W     = (const float*)d_in[25];
    const float* out_b     = (const float*)d_in[26];
    float* out = (float*)d_out;

    // ---- workspace carve-up (floats) -------------------------------------
    float* w = (float*)d_ws;
    auto alloc = [&](size_t n) { float* p = w; w += n; return p; };
    float* Wz       = alloc((size_t)4096 * 2560);  // concat cell weight
    float* x_emb    = alloc((size_t)48 * 64 * 512);
    float* y_emb    = alloc((size_t)48 * 64 * 512);
    float* preA_f   = alloc((size_t)48 * 64 * 2048);
    float* preA_r   = alloc((size_t)48 * 64 * 2048);
    float* out_f    = alloc((size_t)48 * 64 * 512);
    float* out_r    = alloc((size_t)48 * 64 * 512);
    float* ctx      = alloc((size_t)48 * 64 * 1024);
    float* ctx_mean = alloc((size_t)64 * 1024);
    float* att_ctx  = alloc((size_t)48 * 64 * 512);
    float* preY     = alloc((size_t)48 * 64 * 512);
    float* hcbuf    = alloc((size_t)4 * 64 * 512);  // h_f,c_f,h_r,c_r contiguous
    float* h_f = hcbuf, *c_f = hcbuf + 32768, *h_r = hcbuf + 65536, *c_r = hcbuf + 98304;
    float* z_enc_f  = alloc((size_t)64 * 2048);
    float* z_enc_r  = alloc((size_t)64 * 2048);
    float* ht       = alloc((size_t)64 * 1024);
    float* ct       = alloc((size_t)64 * 1024);
    float* hW1h     = alloc((size_t)64 * 512);
    float* cat3     = alloc((size_t)64 * 2560);     // [ctx_t | ht | y_emb]
    float* zbuf     = alloc((size_t)64 * 4096);
    float* r_pre    = alloc((size_t)64 * 1024);
    float* logits   = alloc((size_t)64 * 32000);
    float* lossbuf  = alloc((size_t)48 * 64);
    (void)ws_size; (void)in_sizes; (void)n_in; (void)out_size;

    // ---- setup (parallel) -------------------------------------------------
    hipLaunchKernelGGL(build_wz, dim3(40960), dim3(256), 0, stream, cell_Wih, cell_Whh, Wz);
    hipLaunchKernelGGL(embed_kernel, dim3(6144, 2), dim3(256), 0, stream,
                       x_data, x_mask, y_data, src_emb, dec_emb, x_emb, y_emb);
    // x_emb @ enc_Wih^T + b, both directions in one launch
    gemm(stream, 0, 0, x_emb, 512, enc_Wih_f, 512, enc_b_f, nullptr, preA_f, 3072, 2048, 512,
         x_emb, enc_Wih_r, enc_b_r, nullptr, preA_r);
    hipLaunchKernelGGL(zero_kernel, dim3(512), dim3(256), 0, stream, hcbuf);

    // ---- encoder recurrence (48 steps, fwd+rev dual) ----------------------
    for (int s = 0; s < 48; ++s) {
        gemm(stream, 0, 0, h_f, 512, enc_Whh_f, 512, nullptr,
             preA_f + (size_t)s * 64 * 2048, z_enc_f, 64, 2048, 512,
             h_r, enc_Whh_r, nullptr, preA_r + (size_t)(47 - s) * 64 * 2048, z_enc_r);
        hipLaunchKernelGGL(enc_gates, dim3(128, 2), dim3(256), 0, stream,
                           z_enc_f, z_enc_r, h_f, c_f, h_r, c_r, out_f, out_r, s, 47 - s);
    }

    // ---- context, init states, attention precomputes ----------------------
    hipLaunchKernelGGL(build_ctx, dim3(12288), dim3(256), 0, stream, out_f, out_r, x_mask, ctx);
    hipLaunchKernelGGL(ctx_mean_k, dim3(64), dim3(256), 0, stream, ctx, x_mask, ctx_mean);
    // ht = tanh(cm @ h0_W^T + b), ct = tanh(cm @ c0_W^T + b)  (dual)
    gemm(stream, 1, 0, ctx_mean, 1024, h0_W, 1024, h0_b, nullptr, ht, 64, 1024, 1024,
         ctx_mean, c0_W, c0_b, nullptr, ct);
    hipLaunchKernelGGL(ht_to_cat3, dim3(256), dim3(256), 0, stream, ht, cat3);
    // att_ctx = ctx @ W1c^T + att1_b   (W1c = att1_W[:, 0:1024])
    gemm(stream, 0, 0, ctx, 1024, att1_W, 2560, att1_b, nullptr, att_ctx, 3072, 512, 1024);
    // preY = y_emb @ W1y^T             (W1y = att1_W[:, 1024:1536])
    gemm(stream, 0, 0, y_emb, 512, att1_W + 1024, 2560, nullptr, nullptr, preY, 3072, 512, 512);

    // ---- decoder (48 steps) ------------------------------------------------
    for (int t = 0; t < 48; ++t) {
        // hW1h = ht @ W1h^T  (W1h = att1_W[:, 1536:2560])
        gemm(stream, 0, 0, ht, 1024, att1_W + 1536, 2560, nullptr, nullptr, hW1h, 64, 512, 1024);
        hipLaunchKernelGGL(att_step, dim3(64), dim3(512), 0, stream,
                           att_ctx, preY + (size_t)t * 64 * 512, hW1h, att2_W, att2_b,
                           x_mask, ctx, y_emb + (size_t)t * 64 * 512, cat3);
        // z = cat3 @ Wz^T + cell_b   (cat3 ht slot still holds OLD ht)
        gemm(stream, 0, 0, cat3, 2560, Wz, 2560, cell_b, nullptr, zbuf, 64, 4096, 2560);
        hipLaunchKernelGGL(dec_gates, dim3(256), dim3(256), 0, stream, zbuf, ht, ct, cat3);
        // r_pre = cat3 @ read_W^T + read_b  (cat3 now has NEW ht; order matches read_W)
        gemm(stream, 0, 0, cat3, 2560, read_W, 2560, read_b, nullptr, r_pre, 64, 1024, 2560);
        // logits = maxpair(r_pre) @ out_W^T + out_b
        gemm(stream, 0, 1, r_pre, 1024, out_W, 512, out_b, nullptr, logits, 64, 32000, 512);
        hipLaunchKernelGGL(lsm_nll, dim3(64), dim3(256), 0, stream,
                           logits, y_data + t * 64, y_mask + t * 64, lossbuf + t * 64);
    }

    hipLaunchKernelGGL(final_sum, dim3(1), dim3(256), 0, stream, lossbuf, out);
}

// Round 2
// 6490.435 us; speedup vs baseline: 3.0144x; 3.0144x over previous
//
#include <hip/hip_runtime.h>
#include <hip/hip_bf16.h>
#include <math.h>

// Tx=48 Ty=48 Bn=64 DW=512 E=512 D=1024 A=512 VS=VT=32000
typedef __attribute__((ext_vector_type(8))) short bf16x8;
typedef __attribute__((ext_vector_type(4))) float f32x4;
typedef unsigned short u16;

__device__ __forceinline__ float bf2f(u16 u) {
    union { float f; unsigned i; } v; v.i = ((unsigned)u) << 16; return v.f;
}
__device__ __forceinline__ u16 f2bf(float x) {
    union { float f; unsigned u; } v; v.f = x;
    unsigned r = v.u + 0x7FFF + ((v.u >> 16) & 1);
    return (u16)(r >> 16);
}
__device__ __forceinline__ float sigf(float x) { return 1.0f / (1.0f + expf(-x)); }

// ---------------------------------------------------------------------------
// MFMA GEMM: C[M,N] = act( A_bf16[M,K] @ B_bf16[N,K]^T + bias + Cin_bf16 )
// Block 256 thr = 4 waves (2x2), tile 64x64, wave tile 32x32, K-step 32.
// Fragment k-mapping: lane group lg=lane>>4 covers k = lg*8 + (0..7) for BOTH
// A and B -> any HW k-permutation cancels. C/D: col=lane&15, row=4*lg+reg
// (m89-verified). blockIdx.z==1 selects dual problem.
// ---------------------------------------------------------------------------
template<int OUTBF, int ACT, int CIN>
__global__ __launch_bounds__(256) void mgemm(
    const u16* __restrict__ A, int lda,
    const u16* __restrict__ B, int ldb,
    const float* __restrict__ bias,
    const u16* __restrict__ Cin,
    void* __restrict__ Cout,
    int N, int K,
    const u16* A2, const u16* B2, const float* bias2, const u16* Cin2, void* Cout2)
{
    if (blockIdx.z == 1) { A = A2; B = B2; bias = bias2; Cin = Cin2; Cout = Cout2; }
    const int lane = threadIdx.x & 63;
    const int wave = threadIdx.x >> 6;
    const int wm = wave >> 1, wn = wave & 1;
    const int lr = lane & 15, lg = lane >> 4;
    const size_t bm = (size_t)blockIdx.y * 64, bn = (size_t)blockIdx.x * 64;
    const u16* Ap = A + (bm + wm * 32 + lr) * (size_t)lda + lg * 8;
    const u16* Bp = B + (bn + wn * 32 + lr) * (size_t)ldb + lg * 8;
    f32x4 acc[2][2] = {};
    for (int k0 = 0; k0 < K; k0 += 32) {
        bf16x8 a0 = *(const bf16x8*)(Ap + k0);
        bf16x8 a1 = *(const bf16x8*)(Ap + k0 + 16 * (size_t)lda);
        bf16x8 b0 = *(const bf16x8*)(Bp + k0);
        bf16x8 b1 = *(const bf16x8*)(Bp + k0 + 16 * (size_t)ldb);
        acc[0][0] = __builtin_amdgcn_mfma_f32_16x16x32_bf16(a0, b0, acc[0][0], 0, 0, 0);
        acc[0][1] = __builtin_amdgcn_mfma_f32_16x16x32_bf16(a0, b1, acc[0][1], 0, 0, 0);
        acc[1][0] = __builtin_amdgcn_mfma_f32_16x16x32_bf16(a1, b0, acc[1][0], 0, 0, 0);
        acc[1][1] = __builtin_amdgcn_mfma_f32_16x16x32_bf16(a1, b1, acc[1][1], 0, 0, 0);
    }
    #pragma unroll
    for (int fi = 0; fi < 2; ++fi)
    #pragma unroll
    for (int fj = 0; fj < 2; ++fj) {
        size_t col = bn + wn * 32 + fj * 16 + lr;
        float bv = bias ? bias[col] : 0.0f;
        #pragma unroll
        for (int r = 0; r < 4; ++r) {
            size_t row = bm + wm * 32 + fi * 16 + lg * 4 + r;
            float v = acc[fi][fj][r] + bv;
            if constexpr (CIN) v += bf2f(Cin[row * (size_t)N + col]);
            if constexpr (ACT) v = tanhf(v);
            if constexpr (OUTBF) ((u16*)Cout)[row * (size_t)N + col] = f2bf(v);
            else                 ((float*)Cout)[row * (size_t)N + col] = v;
        }
    }
}

// ---------------------------------------------------------------------------
// Fused logits GEMM + partial log-softmax.
// A = rmax bf16 [3072][512], B = out_W bf16 [32000][512]. Grid (500, 48).
// Per block: 64x64 logits tile (+out_b); per-row max & sum-exp over its 64
// cols -> part[row][bx]; lane holding col==y writes logy[row].
// ---------------------------------------------------------------------------
__global__ __launch_bounds__(256) void logits_lsm(
    const u16* __restrict__ A, const u16* __restrict__ B,
    const float* __restrict__ outb, const int* __restrict__ ydata,
    float2* __restrict__ part, float* __restrict__ logy)
{
    const int lane = threadIdx.x & 63;
    const int wave = threadIdx.x >> 6;
    const int wm = wave >> 1, wn = wave & 1;
    const int lr = lane & 15, lg = lane >> 4;
    const size_t bm = (size_t)blockIdx.y * 64, bn = (size_t)blockIdx.x * 64;
    const u16* Ap = A + (bm + wm * 32 + lr) * 512 + lg * 8;
    const u16* Bp = B + (bn + wn * 32 + lr) * 512 + lg * 8;
    f32x4 acc[2][2] = {};
    for (int k0 = 0; k0 < 512; k0 += 32) {
        bf16x8 a0 = *(const bf16x8*)(Ap + k0);
        bf16x8 a1 = *(const bf16x8*)(Ap + k0 + 16 * 512);
        bf16x8 b0 = *(const bf16x8*)(Bp + k0);
        bf16x8 b1 = *(const bf16x8*)(Bp + k0 + 16 * 512);
        acc[0][0] = __builtin_amdgcn_mfma_f32_16x16x32_bf16(a0, b0, acc[0][0], 0, 0, 0);
        acc[0][1] = __builtin_amdgcn_mfma_f32_16x16x32_bf16(a0, b1, acc[0][1], 0, 0, 0);
        acc[1][0] = __builtin_amdgcn_mfma_f32_16x16x32_bf16(a1, b0, acc[1][0], 0, 0, 0);
        acc[1][1] = __builtin_amdgcn_mfma_f32_16x16x32_bf16(a1, b1, acc[1][1], 0, 0, 0);
    }
    __shared__ float sm[64][2];
    __shared__ float ss[64][2];
    const float b0 = outb[bn + wn * 32 + lr];
    const float b1 = outb[bn + wn * 32 + 16 + lr];
    #pragma unroll
    for (int fi = 0; fi < 2; ++fi) {
        #pragma unroll
        for (int r = 0; r < 4; ++r) {
            int rloc = wm * 32 + fi * 16 + lg * 4 + r;
            size_t row = bm + rloc;
            float v0 = acc[fi][0][r] + b0;
            float v1 = acc[fi][1][r] + b1;
            int yt = ydata[row];
            if (yt == (int)(bn + wn * 32 + lr))      logy[row] = v0;
            if (yt == (int)(bn + wn * 32 + 16 + lr)) logy[row] = v1;
            float m = fmaxf(v0, v1);
            #pragma unroll
            for (int sh = 1; sh < 16; sh <<= 1) m = fmaxf(m, __shfl_xor(m, sh));
            float s = expf(v0 - m) + expf(v1 - m);
            #pragma unroll
            for (int sh = 1; sh < 16; sh <<= 1) s += __shfl_xor(s, sh);
            if (lr == 0) { sm[rloc][wn] = m; ss[rloc][wn] = s; }
        }
    }
    __syncthreads();
    if (threadIdx.x < 64) {
        float m0 = sm[threadIdx.x][0], m1 = sm[threadIdx.x][1];
        float m = fmaxf(m0, m1);
        float s = ss[threadIdx.x][0] * expf(m0 - m) + ss[threadIdx.x][1] * expf(m1 - m);
        part[(bm + threadIdx.x) * 500 + blockIdx.x] = make_float2(m, s);
    }
}

__global__ __launch_bounds__(64) void lsm_reduce(
    const float2* __restrict__ part, const float* __restrict__ logy,
    const float* __restrict__ ymask, float* __restrict__ lossb)
{
    int r = blockIdx.x, lane = threadIdx.x;
    float m = -1e30f;
    for (int i = lane; i < 500; i += 64) m = fmaxf(m, part[(size_t)r * 500 + i].x);
    #pragma unroll
    for (int sh = 32; sh; sh >>= 1) m = fmaxf(m, __shfl_xor(m, sh));
    float s = 0.f;
    for (int i = lane; i < 500; i += 64) {
        float2 p = part[(size_t)r * 500 + i];
        s += p.y * expf(p.x - m);
    }
    #pragma unroll
    for (int sh = 32; sh; sh >>= 1) s += __shfl_xor(s, sh);
    if (lane == 0) {
        float lp = logy[r] - m - logf(s);
        lossb[r] = -lp * ymask[r] * (1.0f / 64.0f);
    }
}

// ---------------------------------------------------------------------------
// Small kernels
// ---------------------------------------------------------------------------
__global__ void convb(const float* __restrict__ src, int sld, int K,
                      u16* __restrict__ dst, int total)
{
    int idx = blockIdx.x * 256 + threadIdx.x;
    if (idx >= total) return;
    int n = idx / K, k = idx - n * K;
    dst[idx] = f2bf(src[(size_t)n * sld + k]);
}

__global__ void build_wz(const float* __restrict__ Wih, const float* __restrict__ Whh,
                         u16* __restrict__ Wz)
{
    int idx = blockIdx.x * 256 + threadIdx.x;   // 4096*2560
    int j = idx % 2560, n = idx / 2560;
    float v;
    if (j < 1024)      v = Wih[(size_t)n * 1536 + 512 + j];
    else if (j < 2048) v = Whh[(size_t)n * 1024 + (j - 1024)];
    else               v = Wih[(size_t)n * 1536 + (j - 2048)];
    Wz[idx] = f2bf(v);
}

__global__ void embed_kernel(const int* __restrict__ xd, const float* __restrict__ xm,
                             const int* __restrict__ yd,
                             const float* __restrict__ src_emb, const float* __restrict__ dec_emb,
                             u16* __restrict__ x_emb, u16* __restrict__ y_emb)
{
    int idx = blockIdx.x * 256 + threadIdx.x;   // 48*64*512
    int d = idx & 511;
    int tb = idx >> 9;
    if (blockIdx.y == 0) {
        int v = xd[tb];
        x_emb[idx] = f2bf(src_emb[(size_t)v * 512 + d] * xm[tb]);
    } else {
        int t = tb >> 6, b = tb & 63;
        int v = (t == 0) ? 0 : yd[(t - 1) * 64 + b];
        y_emb[idx] = f2bf(dec_emb[(size_t)v * 512 + d]);
    }
}

__global__ void enc_gates(const float* __restrict__ z_f, const float* __restrict__ z_r,
                          u16* __restrict__ h_f, float* __restrict__ c_f,
                          u16* __restrict__ h_r, float* __restrict__ c_r,
                          const float* __restrict__ xm,
                          u16* __restrict__ ctxB, int t_f, int t_r)
{
    int dir = blockIdx.y;
    int idx = blockIdx.x * 256 + threadIdx.x;   // 64*512
    int b = idx >> 9, d = idx & 511;
    const float* z = dir ? z_r : z_f;
    u16* h = dir ? h_r : h_f;
    float* c = dir ? c_r : c_f;
    int t = dir ? t_r : t_f;
    float iv = z[b * 2048 + d];
    float fv = z[b * 2048 + 512 + d];
    float gv = z[b * 2048 + 1024 + d];
    float ov = z[b * 2048 + 1536 + d];
    float cn = sigf(fv) * c[idx] + sigf(iv) * tanhf(gv);
    float hn = sigf(ov) * tanhf(cn);
    c[idx] = cn; h[idx] = f2bf(hn);
    ctxB[(size_t)(t * 64 + b) * 1024 + dir * 512 + d] = f2bf(hn * xm[t * 64 + b]);
}

__global__ __launch_bounds__(256) void ctx_mean_k(const u16* __restrict__ ctxB,
                                                  const float* __restrict__ xm,
                                                  u16* __restrict__ cm)
{
    int b = blockIdx.x, tid = threadIdx.x;
    float msum = 0.f;
    for (int t = 0; t < 48; ++t) msum += xm[t * 64 + b];
    float inv = 1.0f / msum;
    for (int e = tid; e < 1024; e += 256) {
        float s = 0.f;
        for (int t = 0; t < 48; ++t)
            s += bf2f(ctxB[(size_t)(t * 64 + b) * 1024 + e]) * xm[t * 64 + b];
        cm[b * 1024 + e] = f2bf(s * inv);
    }
}

__global__ void ht_init(const u16* __restrict__ htB, u16* __restrict__ cat3c)
{
    int idx = blockIdx.x * 256 + threadIdx.x;   // 64*1024
    int b = idx >> 10, d = idx & 1023;
    cat3c[b * 2560 + 1024 + d] = htB[idx];
}

__global__ __launch_bounds__(512) void att_step(
    const u16* __restrict__ attctx, const u16* __restrict__ preY_t,
    const u16* __restrict__ hW1h, const float* __restrict__ att2W,
    const float* __restrict__ att2b, const float* __restrict__ xmask,
    const u16* __restrict__ ctxB, const u16* __restrict__ yemb_t,
    u16* __restrict__ cat3cell, u16* __restrict__ cat3read_t)
{
    int b = blockIdx.x, tid = threadIdx.x;
    __shared__ float sv[512];
    __shared__ float a2s[64];
    sv[tid] = bf2f(preY_t[b * 512 + tid]) + bf2f(hW1h[b * 512 + tid]);
    __syncthreads();
    int wave = tid >> 6, lane = tid & 63;
    for (int tp = wave; tp < 48; tp += 8) {
        const u16* ac = attctx + (size_t)(tp * 64 + b) * 512;
        float s = 0.f;
        #pragma unroll
        for (int a0 = 0; a0 < 512; a0 += 64) {
            int a = a0 + lane;
            s += att2W[a] * tanhf(bf2f(ac[a]) + sv[a]);
        }
        for (int m = 32; m; m >>= 1) s += __shfl_xor(s, m);
        if (lane == 0) a2s[tp] = s + att2b[0];
    }
    __syncthreads();
    if (tid < 64) {
        float v = (tid < 48) ? a2s[tid] : -1e30f;
        float m = v;
        for (int sh = 32; sh; sh >>= 1) m = fmaxf(m, __shfl_xor(m, sh));
        float e = (tid < 48) ? expf(v - m) * xmask[tid * 64 + b] : 0.f;
        float s = e;
        for (int sh = 32; sh; sh >>= 1) s += __shfl_xor(s, sh);
        if (tid < 48) a2s[tid] = e / (s + 1e-15f);
    }
    __syncthreads();
    for (int e0 = tid; e0 < 1024; e0 += 512) {
        float acc = 0.f;
        for (int tp = 0; tp < 48; ++tp)
            acc += a2s[tp] * bf2f(ctxB[(size_t)(tp * 64 + b) * 1024 + e0]);
        u16 cv = f2bf(acc);
        cat3cell[b * 2560 + e0] = cv;
        cat3read_t[b * 2560 + e0] = cv;
    }
    u16 yv = yemb_t[b * 512 + tid];
    cat3cell[b * 2560 + 2048 + tid] = yv;
    cat3read_t[b * 2560 + 2048 + tid] = yv;
}

__global__ void dec_gates(const float* __restrict__ z, float* __restrict__ ct,
                          u16* __restrict__ htB, u16* __restrict__ cat3cell,
                          u16* __restrict__ cat3read_t)
{
    int idx = blockIdx.x * 256 + threadIdx.x;   // 64*1024
    int b = idx >> 10, d = idx & 1023;
    float iv = z[b * 4096 + d];
    float fv = z[b * 4096 + 1024 + d];
    float gv = z[b * 4096 + 2048 + d];
    float ov = z[b * 4096 + 3072 + d];
    float cn = sigf(fv) * ct[idx] + sigf(iv) * tanhf(gv);
    float hn = sigf(ov) * tanhf(cn);
    ct[idx] = cn;
    u16 hb = f2bf(hn);
    htB[idx] = hb;
    cat3cell[b * 2560 + 1024 + d] = hb;
    cat3read_t[b * 2560 + 1024 + d] = hb;
}

__global__ void maxpair(const u16* __restrict__ rB, u16* __restrict__ rmax)
{
    int idx = blockIdx.x * 256 + threadIdx.x;   // 3072*512
    int row = idx >> 9, d = idx & 511;
    float a = bf2f(rB[(size_t)row * 1024 + 2 * d]);
    float b = bf2f(rB[(size_t)row * 1024 + 2 * d + 1]);
    rmax[idx] = f2bf(fmaxf(a, b));
}

__global__ __launch_bounds__(256) void final_sum(const float* __restrict__ lossb,
                                                 float* __restrict__ out)
{
    __shared__ float red[4];
    int tid = threadIdx.x;
    float s = 0.f;
    for (int i = tid; i < 3072; i += 256) s += lossb[i];
    for (int sh = 32; sh; sh >>= 1) s += __shfl_xor(s, sh);
    if ((tid & 63) == 0) red[tid >> 6] = s;
    __syncthreads();
    if (tid == 0) out[0] = red[0] + red[1] + red[2] + red[3];
}

// ---------------------------------------------------------------------------
// Host
// ---------------------------------------------------------------------------
template<int OUTBF, int ACT, int CIN>
static void mg(hipStream_t st, dim3 grid,
               const u16* A, int lda, const u16* B, int ldb,
               const float* bias, const u16* Cin, void* C, int N, int K,
               const u16* A2 = nullptr, const u16* B2 = nullptr,
               const float* bias2 = nullptr, const u16* Cin2 = nullptr, void* C2 = nullptr)
{
    hipLaunchKernelGGL((mgemm<OUTBF, ACT, CIN>), grid, dim3(256), 0, st,
                       A, lda, B, ldb, bias, Cin, C, N, K, A2, B2, bias2, Cin2, C2);
}

extern "C" void kernel_launch(void* const* d_in, const int* in_sizes, int n_in,
                              void* d_out, int out_size, void* d_ws, size_t ws_size,
                              hipStream_t stream)
{
    const int*   x_data    = (const int*)d_in[0];
    const float* x_mask    = (const float*)d_in[1];
    const int*   y_data    = (const int*)d_in[2];
    const float* y_mask    = (const float*)d_in[3];
    const float* src_emb   = (const float*)d_in[4];
    const float* dec_emb   = (const float*)d_in[5];
    const float* enc_Wih_f = (const float*)d_in[6];
    const float* enc_Whh_f = (const float*)d_in[7];
    const float* enc_b_f   = (const float*)d_in[8];
    const float* enc_Wih_r = (const float*)d_in[9];
    const float* enc_Whh_r = (const float*)d_in[10];
    const float* enc_b_r   = (const float*)d_in[11];
    const float* h0_W      = (const float*)d_in[12];
    const float* h0_b      = (const float*)d_in[13];
    const float* c0_W      = (const float*)d_in[14];
    const float* c0_b      = (const float*)d_in[15];
    const float* att1_W    = (const float*)d_in[16];
    const float* att1_b    = (const float*)d_in[17];
    const float* att2_W    = (const float*)d_in[18];
    const float* att2_b    = (const float*)d_in[19];
    const float* cell_Wih  = (const float*)d_in[20];
    const float* cell_Whh  = (const float*)d_in[21];
    const float* cell_b    = (const float*)d_in[22];
    const float* read_W    = (const float*)d_in[23];
    const float* read_b    = (const float*)d_in[24];
    const float* out_W     = (const float*)d_in[25];
    const float* out_b     = (const float*)d_in[26];
    float* out = (float*)d_out;
    (void)in_sizes; (void)n_in; (void)out_size; (void)ws_size;

    char* base = (char*)d_ws;
    size_t off = 0;
    auto ab = [&](size_t bytes) -> void* {
        void* p = base + off;
        off += (bytes + 255) & ~(size_t)255;
        return p;
    };
    u16* WzB     = (u16*)ab(4096UL * 2560 * 2);
    u16* outWB   = (u16*)ab(32000UL * 512 * 2);
    u16* readWB  = (u16*)ab(1024UL * 2560 * 2);
    u16* WihFB   = (u16*)ab(2048UL * 512 * 2);
    u16* WihRB   = (u16*)ab(2048UL * 512 * 2);
    u16* WhhFB   = (u16*)ab(2048UL * 512 * 2);
    u16* WhhRB   = (u16*)ab(2048UL * 512 * 2);
    u16* h0WB    = (u16*)ab(1024UL * 1024 * 2);
    u16* c0WB    = (u16*)ab(1024UL * 1024 * 2);
    u16* W1cB    = (u16*)ab(512UL * 1024 * 2);
    u16* W1yB    = (u16*)ab(512UL * 512 * 2);
    u16* W1hB    = (u16*)ab(512UL * 1024 * 2);
    u16* xembB   = (u16*)ab(3072UL * 512 * 2);
    u16* yembB   = (u16*)ab(3072UL * 512 * 2);
    u16* preAF   = (u16*)ab(3072UL * 2048 * 2);
    u16* preAR   = (u16*)ab(3072UL * 2048 * 2);
    u16* ctxB    = (u16*)ab(3072UL * 1024 * 2);
    u16* attctxB = (u16*)ab(3072UL * 512 * 2);
    u16* preYB   = (u16*)ab(3072UL * 512 * 2);
    u16* cmB     = (u16*)ab(64UL * 1024 * 2);
    u16* hFB     = (u16*)ab(64UL * 512 * 2);    // start of zero region
    u16* hRB     = (u16*)ab(64UL * 512 * 2);
    float* cF    = (float*)ab(64UL * 512 * 4);
    float* cR    = (float*)ab(64UL * 512 * 4);  // end of zero region
    float* zencF = (float*)ab(64UL * 2048 * 4);
    float* zencR = (float*)ab(64UL * 2048 * 4);
    u16* htB     = (u16*)ab(64UL * 1024 * 2);
    float* ctF   = (float*)ab(64UL * 1024 * 4);
    u16* hW1hB   = (u16*)ab(64UL * 512 * 2);
    u16* cat3c   = (u16*)ab(64UL * 2560 * 2);
    u16* cat3r   = (u16*)ab(3072UL * 2560 * 2);
    float* zbuf  = (float*)ab(64UL * 4096 * 4);
    u16* rB      = (u16*)ab(3072UL * 1024 * 2);
    u16* rmaxB   = (u16*)ab(3072UL * 512 * 2);
    float2* part = (float2*)ab(3072UL * 500 * 8);
    float* logy  = (float*)ab(3072UL * 4);
    float* lossb = (float*)ab(3072UL * 4);

    // ---- setup: converts, embeds, zero states -----------------------------
    hipMemsetAsync(hFB, 0, 64UL * 512 * 2 * 2 + 64UL * 512 * 4 * 2, stream);
    hipLaunchKernelGGL(build_wz, dim3(40960), dim3(256), 0, stream, cell_Wih, cell_Whh, WzB);
    auto conv = [&](const float* src, int sld, int K, u16* dst, size_t total) {
        hipLaunchKernelGGL(convb, dim3((unsigned)((total + 255) / 256)), dim3(256), 0, stream,
                           src, sld, K, dst, (int)total);
    };
    conv(out_W, 512, 512, outWB, 32000UL * 512);
    conv(read_W, 2560, 2560, readWB, 1024UL * 2560);
    conv(enc_Wih_f, 512, 512, WihFB, 2048UL * 512);
    conv(enc_Wih_r, 512, 512, WihRB, 2048UL * 512);
    conv(enc_Whh_f, 512, 512, WhhFB, 2048UL * 512);
    conv(enc_Whh_r, 512, 512, WhhRB, 2048UL * 512);
    conv(h0_W, 1024, 1024, h0WB, 1024UL * 1024);
    conv(c0_W, 1024, 1024, c0WB, 1024UL * 1024);
    conv(att1_W, 2560, 1024, W1cB, 512UL * 1024);
    conv(att1_W + 1024, 2560, 512, W1yB, 512UL * 512);
    conv(att1_W + 1536, 2560, 1024, W1hB, 512UL * 1024);
    hipLaunchKernelGGL(embed_kernel, dim3(6144, 2), dim3(256), 0, stream,
                       x_data, x_mask, y_data, src_emb, dec_emb, xembB, yembB);

    // preA = x_emb @ Wih^T + b (both dirs, dual)
    mg<1, 0, 0>(stream, dim3(32, 48, 2), xembB, 512, WihFB, 512, enc_b_f, nullptr,
                preAF, 2048, 512, xembB, WihRB, enc_b_r, nullptr, preAR);

    // ---- encoder recurrence ----------------------------------------------
    for (int t = 0; t < 48; ++t) {
        mg<0, 0, 1>(stream, dim3(32, 1, 2), hFB, 512, WhhFB, 512, nullptr,
                    preAF + (size_t)t * 64 * 2048, zencF, 2048, 512,
                    hRB, WhhRB, nullptr, preAR + (size_t)(47 - t) * 64 * 2048, zencR);
        hipLaunchKernelGGL(enc_gates, dim3(128, 2), dim3(256), 0, stream,
                           zencF, zencR, hFB, cF, hRB, cR, x_mask, ctxB, t, 47 - t);
    }

    // ---- init states + attention precomputes ------------------------------
    hipLaunchKernelGGL(ctx_mean_k, dim3(64), dim3(256), 0, stream, ctxB, x_mask, cmB);
    mg<1, 1, 0>(stream, dim3(16, 1, 1), cmB, 1024, h0WB, 1024, h0_b, nullptr, htB, 1024, 1024);
    mg<0, 1, 0>(stream, dim3(16, 1, 1), cmB, 1024, c0WB, 1024, c0_b, nullptr, ctF, 1024, 1024);
    hipLaunchKernelGGL(ht_init, dim3(256), dim3(256), 0, stream, htB, cat3c);
    mg<1, 0, 0>(stream, dim3(8, 48, 1), ctxB, 1024, W1cB, 1024, att1_b, nullptr, attctxB, 512, 1024);
    mg<1, 0, 0>(stream, dim3(8, 48, 1), yembB, 512, W1yB, 512, nullptr, nullptr, preYB, 512, 512);

    // ---- decoder recurrence ----------------------------------------------
    for (int t = 0; t < 48; ++t) {
        mg<1, 0, 0>(stream, dim3(8, 1, 1), htB, 1024, W1hB, 1024, nullptr, nullptr, hW1hB, 512, 1024);
        hipLaunchKernelGGL(att_step, dim3(64), dim3(512), 0, stream,
                           attctxB, preYB + (size_t)t * 64 * 512, hW1hB, att2_W, att2_b,
                           x_mask, ctxB, yembB + (size_t)t * 64 * 512,
                           cat3c, cat3r + (size_t)t * 64 * 2560);
        mg<0, 0, 0>(stream, dim3(64, 1, 1), cat3c, 2560, WzB, 2560, cell_b, nullptr, zbuf, 4096, 2560);
        hipLaunchKernelGGL(dec_gates, dim3(256), dim3(256), 0, stream,
                           zbuf, ctF, htB, cat3c, cat3r + (size_t)t * 64 * 2560);
    }

    // ---- batched read / maxpair / logits+lsm / loss -----------------------
    mg<1, 0, 0>(stream, dim3(16, 48, 1), cat3r, 2560, readWB, 2560, read_b, nullptr, rB, 1024, 2560);
    hipLaunchKernelGGL(maxpair, dim3(6144), dim3(256), 0, stream, rB, rmaxB);
    hipLaunchKernelGGL(logits_lsm, dim3(500, 48), dim3(256), 0, stream,
                       rmaxB, outWB, out_b, y_data, part, logy);
    hipLaunchKernelGGL(lsm_reduce, dim3(3072), dim3(64), 0, stream, part, logy, y_mask, lossb);
    hipLaunchKernelGGL(final_sum, dim3(1), dim3(256), 0, stream, lossb, out);
}